// Round 4
// baseline (805.719 us; speedup 1.0000x reference)
//
#include <hip/hip_runtime.h>

// 4-layer 5-point cross-stencil CNN, implicit GEMM on MFMA (MI355X gfx950).
// Round 4: latency-bound fix. Wave owns M (2 rows x 16 px) and iterates all
// 8 n-frags -> each ds_read_b128 A-frag feeds 16 MFMAs (128 MAC/B).
// Weights K-major W[ks][oc][32] so B loads are 1KB/wave coalesced and
// identical across waves (L1 broadcast). L1 layer is MFMA now (K=30 pad 32).
// All MFMA layouts are the round-3-verified 16x16x32_f16 mappings:
//   A[m=lane&15][k=quad*8+j], B[n=lane&15][k=quad*8+j], C: col=lane&15,
//   row=quad*4+reg.   Taps: 0=c,1=up,2=down,3=left,4=right.

#define BB   8
#define HH   256
#define WW   256

typedef _Float16 f16x8 __attribute__((ext_vector_type(8)));
typedef float    f32x4 __attribute__((ext_vector_type(4)));

// K-major fp16 weight tables (rewritten every launch by prep).
__device__ _Float16 W1g[128 * 32];       // [oc][k], k=tap*6+ic, 30..31 = 0
__device__ _Float16 W2g[20 * 128 * 32];  // [ks=tap*4+kc][oc][icb]
__device__ _Float16 W3g[20 * 128 * 32];
__device__ _Float16 W4g[5 * 16 * 128];   // [tap][oc(pad16)][ic]  (round-3 g4 layout)

__global__ void prep(const float* __restrict__ w1, const float* __restrict__ w2,
                     const float* __restrict__ w3, const float* __restrict__ w4)
{
    int idx = blockIdx.x * 256 + threadIdx.x;
    if (idx < 81920) {                                  // W2g
        int icb = idx & 31, oc = (idx >> 5) & 127, ks = idx >> 12;
        int tap = ks >> 2, ic = (ks & 3) * 32 + icb;
        W2g[idx] = (_Float16)w2[(oc * 128 + ic) * 5 + tap];
    } else if (idx < 163840) {                          // W3g
        int k = idx - 81920;
        int icb = k & 31, oc = (k >> 5) & 127, ks = k >> 12;
        int tap = ks >> 2, ic = (ks & 3) * 32 + icb;
        W3g[k] = (_Float16)w3[(oc * 128 + ic) * 5 + tap];
    } else if (idx < 174080) {                          // W4g (old layout)
        int k = idx - 163840;
        int t = k / 2048, oc = (k >> 7) & 15, ic = k & 127;
        W4g[k] = (_Float16)((oc < 6) ? w4[(oc * 128 + ic) * 5 + t] : 0.f);
    } else if (idx < 178176) {                          // W1g
        int k = idx - 174080;
        int kk = k & 31, oc = k >> 5;
        float v = 0.f;
        if (kk < 30) {
            int tap = (kk * 43) >> 8;                   // kk/6 for kk<30
            int ic = kk - 6 * tap;
            v = w1[(oc * 6 + ic) * 5 + tap];
        }
        W1g[k] = (_Float16)v;
    }
}

// ---------------- L1: MFMA, K=32 (tap*6+ic, padded). NCHW fp32 -> NHWC fp16.
// Block: 8 rows x 16 px (M=128). Gathered A-panel [px128][k32] stride 40.
__global__ __launch_bounds__(256, 3) void g1(
    const float* __restrict__ x, const float* __restrict__ bias,
    _Float16* __restrict__ outp)
{
    __shared__ _Float16 Ap[128 * 40];
    const int tid = threadIdx.x;
    const int j0 = blockIdx.x * 16, i0 = blockIdx.y * 8, b = blockIdx.z;
    const int px = tid & 127, half = tid >> 7;
    const int pr = px >> 4, pp = px & 15;
#pragma unroll
    for (int it = 0; it < 16; ++it) {
        int k = it * 2 + half;
        float v = 0.f;
        if (k < 30) {
            int tap = (k * 43) >> 8, ic = k - 6 * tap;
            int di = (tap == 1) ? -1 : ((tap == 2) ? 1 : 0);
            int dj = (tap == 3) ? -1 : ((tap == 4) ? 1 : 0);
            int gi = i0 + pr + di, gj = j0 + pp + dj;
            if (((unsigned)gi < 256u) && ((unsigned)gj < 256u))
                v = x[(((size_t)b * 6 + ic) * 256 + gi) * 256 + gj];
        }
        Ap[px * 40 + k] = (_Float16)v;
    }
    __syncthreads();

    const int lane = tid & 63, w = tid >> 6, l16 = lane & 15, quad = lane >> 4;
    f32x4 acc[2][8] = {};
    f16x8 a0 = *(const f16x8*)&Ap[((2 * w + 0) * 16 + l16) * 40 + quad * 8];
    f16x8 a1 = *(const f16x8*)&Ap[((2 * w + 1) * 16 + l16) * 40 + quad * 8];
#pragma unroll
    for (int nf = 0; nf < 8; ++nf) {
        f16x8 bf = *(const f16x8*)&W1g[(nf * 16 + l16) * 32 + quad * 8];
        acc[0][nf] = __builtin_amdgcn_mfma_f32_16x16x32_f16(a0, bf, acc[0][nf], 0, 0, 0);
        acc[1][nf] = __builtin_amdgcn_mfma_f32_16x16x32_f16(a1, bf, acc[1][nf], 0, 0, 0);
    }
#pragma unroll
    for (int mf = 0; mf < 2; ++mf) {
        const size_t rowb = ((size_t)b * 256 + i0 + 2 * w + mf) * 256 + j0;
#pragma unroll
        for (int nf = 0; nf < 8; ++nf) {
            const float bv = bias[nf * 16 + l16];
#pragma unroll
            for (int r = 0; r < 4; ++r)
                outp[(rowb + quad * 4 + r) * 128 + nf * 16 + l16] =
                    (_Float16)fmaxf(acc[mf][nf][r] + bv, 0.f);
        }
    }
}

// ---------------- middle layers: M=128 (8 rows x 16 px), N=128, K=640 -------
// Wave w owns rows {2w, 2w+1}; per k-step: 2 ds_read_b128 + 8 coalesced
// B-loads (same addrs across waves) + 16 MFMA. A-panel 10x18x136 = 48.9 KB.
template<int LAYER>
__global__ __launch_bounds__(256, 3) void gmid(
    const _Float16* __restrict__ in, const float* __restrict__ bias,
    _Float16* __restrict__ outp)
{
    const _Float16* wt = (LAYER == 2) ? W2g : W3g;
    __shared__ _Float16 Al[10 * 18 * 136];
    const int tid = threadIdx.x;
    const int j0 = blockIdx.x * 16, i0 = blockIdx.y * 8, b = blockIdx.z;

    for (int t = tid; t < 2880; t += 256) {     // 10 rows x 18 px x 16 chunks
        int r = t / 288, rem = t - r * 288, p = rem >> 4, q = rem & 15;
        int gi = i0 - 1 + r, gj = j0 - 1 + p;
        f16x8 v = {0, 0, 0, 0, 0, 0, 0, 0};
        if (((unsigned)gi < 256u) && ((unsigned)gj < 256u))
            v = *(const f16x8*)&in[(((size_t)b * 256 + gi) * 256 + gj) * 128 + q * 8];
        *(f16x8*)&Al[(r * 18 + p) * 136 + q * 8] = v;
    }
    __syncthreads();

    const int lane = tid & 63, w = tid >> 6, l16 = lane & 15, quad = lane >> 4;
    f32x4 acc[2][8] = {};
    const int DR[5] = {1, 0, 2, 1, 1}, DP[5] = {1, 1, 1, 0, 2};

#pragma unroll
    for (int tap = 0; tap < 5; ++tap) {
#pragma unroll
        for (int kc = 0; kc < 4; ++kc) {
            const int ks = tap * 4 + kc;
            const int koff = kc * 32 + quad * 8;
            f16x8 a0 = *(const f16x8*)&Al[((DR[tap] + 2 * w) * 18 + DP[tap] + l16) * 136 + koff];
            f16x8 a1 = *(const f16x8*)&Al[((DR[tap] + 2 * w + 1) * 18 + DP[tap] + l16) * 136 + koff];
#pragma unroll
            for (int nf = 0; nf < 8; ++nf) {
                f16x8 bf = *(const f16x8*)&wt[(size_t)(ks * 128 + nf * 16 + l16) * 32 + quad * 8];
                acc[0][nf] = __builtin_amdgcn_mfma_f32_16x16x32_f16(a0, bf, acc[0][nf], 0, 0, 0);
                acc[1][nf] = __builtin_amdgcn_mfma_f32_16x16x32_f16(a1, bf, acc[1][nf], 0, 0, 0);
            }
        }
    }

#pragma unroll
    for (int mf = 0; mf < 2; ++mf) {
        const size_t rowb = ((size_t)b * 256 + i0 + 2 * w + mf) * 256 + j0;
#pragma unroll
        for (int nf = 0; nf < 8; ++nf) {
            const float bv = bias[nf * 16 + l16];
#pragma unroll
            for (int r = 0; r < 4; ++r)
                outp[(rowb + quad * 4 + r) * 128 + nf * 16 + l16] =
                    (_Float16)fmaxf(acc[mf][nf][r] + bv, 0.f);
        }
    }
}

// ---------------- L4: 128 -> 6 (pad 16), MFMA, fp32 NCHW out (round-3 code) -
__global__ __launch_bounds__(256, 3) void g4(
    const _Float16* __restrict__ in, const float* __restrict__ bias,
    float* __restrict__ outp)
{
    __shared__ _Float16 Al[6 * 18 * 136];
    const int tid = threadIdx.x;
    const int jt = blockIdx.x, it = blockIdx.y, b = blockIdx.z;
    const int i0 = it * 4, j0 = jt * 16;

    for (int t = tid; t < 6 * 18 * 16; t += 256) {
        int r = t / 288, rem = t % 288, p = rem >> 4, q = rem & 15;
        int gi = i0 - 1 + r, gj = j0 - 1 + p;
        f16x8 v = {0, 0, 0, 0, 0, 0, 0, 0};
        if (((unsigned)gi < 256u) && ((unsigned)gj < 256u))
            v = *(const f16x8*)&in[(((size_t)b * 256 + gi) * 256 + gj) * 128 + q * 8];
        *(f16x8*)&Al[(r * 18 + p) * 136 + q * 8] = v;
    }
    __syncthreads();

    const int lane = tid & 63, wid = tid >> 6;
    const int l16 = lane & 15, quad = lane >> 4;
    f32x4 acc = {};
    const int DR[5] = {1, 0, 2, 1, 1}, DP[5] = {1, 1, 1, 0, 2};

#pragma unroll
    for (int ks = 0; ks < 20; ++ks) {
        const int tap = ks >> 2, kc = ks & 3;
        const int koff = kc * 32 + quad * 8;
        f16x8 bf = *(const f16x8*)&W4g[(size_t)(tap * 16 + l16) * 128 + koff];
        f16x8 af = *(const f16x8*)&Al[((DR[tap] + wid) * 18 + DP[tap] + l16) * 136 + koff];
        acc = __builtin_amdgcn_mfma_f32_16x16x32_f16(af, bf, acc, 0, 0, 0);
    }

    if (l16 < 6) {
        const float bb = bias[l16];
        const int i = i0 + wid;
#pragma unroll
        for (int vi = 0; vi < 4; ++vi) {
            int jj = j0 + quad * 4 + vi;
            outp[(((size_t)b * 6 + l16) << 16) + i * 256 + jj] = acc[vi] + bb;
        }
    }
}

extern "C" void kernel_launch(void* const* d_in, const int* in_sizes, int n_in,
                              void* d_out, int out_size, void* d_ws, size_t ws_size,
                              hipStream_t stream) {
    const float* x  = (const float*)d_in[0];
    const float* w1 = (const float*)d_in[1];
    const float* b1 = (const float*)d_in[2];
    const float* w2 = (const float*)d_in[3];
    const float* b2 = (const float*)d_in[4];
    const float* w3 = (const float*)d_in[5];
    const float* b3 = (const float*)d_in[6];
    const float* w4 = (const float*)d_in[7];
    const float* b4 = (const float*)d_in[8];
    float* out = (float*)d_out;

    const size_t act = (size_t)BB * HH * WW * 128;
    _Float16* A1 = (_Float16*)d_ws;
    _Float16* A2 = A1 + act;                    // exactly 268435456 B total

    prep<<<696, 256, 0, stream>>>(w1, w2, w3, w4);
    dim3 blk(256, 1, 1);
    dim3 gm(16, 32, 8);                         // 16-px x 8-row tiles
    g1<<<gm, blk, 0, stream>>>(x, b1, A1);
    gmid<2><<<gm, blk, 0, stream>>>(A1, b2, A2);
    gmid<3><<<gm, blk, 0, stream>>>(A2, b3, A1);
    g4<<<dim3(16, 64, 8), blk, 0, stream>>>(A1, b4, out);
}

// Round 5
// 518.508 us; speedup vs baseline: 1.5539x; 1.5539x over previous
//
#include <hip/hip_runtime.h>

// 4-layer 5-point cross-stencil CNN, implicit GEMM on MFMA (MI355X gfx950).
// Round 5: fix round-4 latency serialization.
//  - gmid: 2x2 wave grid (wave owns 4 rows x 64 oc), 16 MFMA per k-step per
//    wave fed by 4 LDS A-frags + 4 global B-frags.
//  - EXPLICIT 1-deep software pipeline: A and B fragments for step ks+1 are
//    loaded (source-order) before the MFMAs of step ks, fully unrolled, so
//    prefetch loads stay in flight across the MFMA block (vmcnt(N) pattern).
//  - __launch_bounds__(256,3): 170 VGPR budget, ~148 used; LDS 49KB -> 3 blk/CU.
// MFMA 16x16x32_f16 layouts (verified round 3):
//   A[m=lane&15][k=quad*8+j], B[n=lane&15][k=quad*8+j], C: col=lane&15,
//   row=quad*4+reg.   Taps: 0=c,1=up,2=down,3=left,4=right.

#define BB   8
#define HH   256
#define WW   256

typedef _Float16 f16x8 __attribute__((ext_vector_type(8)));
typedef float    f32x4 __attribute__((ext_vector_type(4)));

// K-major fp16 weight tables (rewritten every launch by prep).
__device__ _Float16 W1g[128 * 32];       // [oc][k], k=tap*6+ic, 30..31 = 0
__device__ _Float16 W2g[20 * 128 * 32];  // [ks=tap*4+kc][oc][icb]
__device__ _Float16 W3g[20 * 128 * 32];
__device__ _Float16 W4g[5 * 16 * 128];   // [tap][oc(pad16)][ic]

__global__ void prep(const float* __restrict__ w1, const float* __restrict__ w2,
                     const float* __restrict__ w3, const float* __restrict__ w4)
{
    int idx = blockIdx.x * 256 + threadIdx.x;
    if (idx < 81920) {                                  // W2g
        int icb = idx & 31, oc = (idx >> 5) & 127, ks = idx >> 12;
        int tap = ks >> 2, ic = (ks & 3) * 32 + icb;
        W2g[idx] = (_Float16)w2[(oc * 128 + ic) * 5 + tap];
    } else if (idx < 163840) {                          // W3g
        int k = idx - 81920;
        int icb = k & 31, oc = (k >> 5) & 127, ks = k >> 12;
        int tap = ks >> 2, ic = (ks & 3) * 32 + icb;
        W3g[k] = (_Float16)w3[(oc * 128 + ic) * 5 + tap];
    } else if (idx < 174080) {                          // W4g
        int k = idx - 163840;
        int t = k / 2048, oc = (k >> 7) & 15, ic = k & 127;
        W4g[k] = (_Float16)((oc < 6) ? w4[(oc * 128 + ic) * 5 + t] : 0.f);
    } else if (idx < 178176) {                          // W1g
        int k = idx - 174080;
        int kk = k & 31, oc = k >> 5;
        float v = 0.f;
        if (kk < 30) {
            int tap = (kk * 43) >> 8;                   // kk/6 for kk<30
            int ic = kk - 6 * tap;
            v = w1[(oc * 6 + ic) * 5 + tap];
        }
        W1g[k] = (_Float16)v;
    }
}

// ---------------- L1: MFMA, K=32 (tap*6+ic, padded). NCHW fp32 -> NHWC fp16.
__global__ __launch_bounds__(256, 3) void g1(
    const float* __restrict__ x, const float* __restrict__ bias,
    _Float16* __restrict__ outp)
{
    __shared__ _Float16 Ap[128 * 40];
    const int tid = threadIdx.x;
    const int j0 = blockIdx.x * 16, i0 = blockIdx.y * 8, b = blockIdx.z;
    const int px = tid & 127, half = tid >> 7;
    const int pr = px >> 4, pp = px & 15;
#pragma unroll
    for (int it = 0; it < 16; ++it) {
        int k = it * 2 + half;
        float v = 0.f;
        if (k < 30) {
            int tap = (k * 43) >> 8, ic = k - 6 * tap;
            int di = (tap == 1) ? -1 : ((tap == 2) ? 1 : 0);
            int dj = (tap == 3) ? -1 : ((tap == 4) ? 1 : 0);
            int gi = i0 + pr + di, gj = j0 + pp + dj;
            if (((unsigned)gi < 256u) && ((unsigned)gj < 256u))
                v = x[(((size_t)b * 6 + ic) * 256 + gi) * 256 + gj];
        }
        Ap[px * 40 + k] = (_Float16)v;
    }
    __syncthreads();

    const int lane = tid & 63, w = tid >> 6, l16 = lane & 15, quad = lane >> 4;
    f32x4 acc[2][8] = {};
    f16x8 a0 = *(const f16x8*)&Ap[((2 * w + 0) * 16 + l16) * 40 + quad * 8];
    f16x8 a1 = *(const f16x8*)&Ap[((2 * w + 1) * 16 + l16) * 40 + quad * 8];
#pragma unroll
    for (int nf = 0; nf < 8; ++nf) {
        f16x8 bf = *(const f16x8*)&W1g[(nf * 16 + l16) * 32 + quad * 8];
        acc[0][nf] = __builtin_amdgcn_mfma_f32_16x16x32_f16(a0, bf, acc[0][nf], 0, 0, 0);
        acc[1][nf] = __builtin_amdgcn_mfma_f32_16x16x32_f16(a1, bf, acc[1][nf], 0, 0, 0);
    }
#pragma unroll
    for (int mf = 0; mf < 2; ++mf) {
        const size_t rowb = ((size_t)b * 256 + i0 + 2 * w + mf) * 256 + j0;
#pragma unroll
        for (int nf = 0; nf < 8; ++nf) {
            const float bv = bias[nf * 16 + l16];
#pragma unroll
            for (int r = 0; r < 4; ++r)
                outp[(rowb + quad * 4 + r) * 128 + nf * 16 + l16] =
                    (_Float16)fmaxf(acc[mf][nf][r] + bv, 0.f);
        }
    }
}

// ---------------- middle layers: M=128 (8 rows x 16 px), N=128, K=640 -------
// 2x2 wave grid: wave(mg,ng) owns rows r0..r0+3 and oc n0..n0+63.
// Explicit 1-deep prefetch (registers) for both A (LDS) and B (global).
template<int LAYER>
__global__ __launch_bounds__(256, 3) void gmid(
    const _Float16* __restrict__ in, const float* __restrict__ bias,
    _Float16* __restrict__ outp)
{
    const _Float16* wt = (LAYER == 2) ? W2g : W3g;
    __shared__ _Float16 Al[10 * 18 * 136];
    const int tid = threadIdx.x;
    const int j0 = blockIdx.x * 16, i0 = blockIdx.y * 8, b = blockIdx.z;

    for (int t = tid; t < 2880; t += 256) {     // 10 rows x 18 px x 16 chunks
        int r = t / 288, rem = t - r * 288, p = rem >> 4, q = rem & 15;
        int gi = i0 - 1 + r, gj = j0 - 1 + p;
        f16x8 v = {0, 0, 0, 0, 0, 0, 0, 0};
        if (((unsigned)gi < 256u) && ((unsigned)gj < 256u))
            v = *(const f16x8*)&in[(((size_t)b * 256 + gi) * 256 + gj) * 128 + q * 8];
        *(f16x8*)&Al[(r * 18 + p) * 136 + q * 8] = v;
    }
    __syncthreads();

    const int lane = tid & 63, w = tid >> 6;
    const int l16 = lane & 15, quad = lane >> 4;
    const int mg = w & 1, ng = w >> 1;
    const int r0 = mg * 4;                       // first of 4 rows
    const int n0 = ng * 64;                      // first of 64 oc

    const _Float16* wb = wt + (size_t)(n0 + l16) * 32 + quad * 8;
    // B frag (ks, nf) at wb + ks*4096 + nf*512

    f32x4 acc[4][4] = {};
    const int DR[5] = {1, 0, 2, 1, 1}, DP[5] = {1, 1, 1, 0, 2};

    f16x8 bc[4], bn[4], ac[4], an[4];
#pragma unroll
    for (int nf = 0; nf < 4; ++nf) bc[nf] = *(const f16x8*)(wb + nf * 512);
#pragma unroll
    for (int r = 0; r < 4; ++r)                  // ks=0: tap0 (DR=1,DP=1), kc=0
        ac[r] = *(const f16x8*)&Al[((1 + r0 + r) * 18 + 1 + l16) * 136 + quad * 8];

#pragma unroll
    for (int ks = 0; ks < 20; ++ks) {
        if (ks < 19) {
            const int t2 = (ks + 1) >> 2, kc2 = (ks + 1) & 3;
            const int ko2 = kc2 * 32 + quad * 8;
#pragma unroll
            for (int nf = 0; nf < 4; ++nf)
                bn[nf] = *(const f16x8*)(wb + (size_t)(ks + 1) * 4096 + nf * 512);
#pragma unroll
            for (int r = 0; r < 4; ++r)
                an[r] = *(const f16x8*)&Al[((DR[t2] + r0 + r) * 18 + DP[t2] + l16) * 136 + ko2];
        }
#pragma unroll
        for (int r = 0; r < 4; ++r)
#pragma unroll
            for (int nf = 0; nf < 4; ++nf)
                acc[r][nf] = __builtin_amdgcn_mfma_f32_16x16x32_f16(ac[r], bc[nf], acc[r][nf], 0, 0, 0);
#pragma unroll
        for (int nf = 0; nf < 4; ++nf) bc[nf] = bn[nf];
#pragma unroll
        for (int r = 0; r < 4; ++r) ac[r] = an[r];
    }

#pragma unroll
    for (int r = 0; r < 4; ++r) {
        const size_t rowb = ((size_t)b * 256 + i0 + r0 + r) * 256 + j0;
#pragma unroll
        for (int nf = 0; nf < 4; ++nf) {
            const float bv = bias[n0 + nf * 16 + l16];
#pragma unroll
            for (int vi = 0; vi < 4; ++vi)
                outp[(rowb + quad * 4 + vi) * 128 + n0 + nf * 16 + l16] =
                    (_Float16)fmaxf(acc[r][nf][vi] + bv, 0.f);
        }
    }
}

// ---------------- L4: 128 -> 6 (pad 16), MFMA, fp32 NCHW out ----------------
__global__ __launch_bounds__(256, 3) void g4(
    const _Float16* __restrict__ in, const float* __restrict__ bias,
    float* __restrict__ outp)
{
    __shared__ _Float16 Al[6 * 18 * 136];
    const int tid = threadIdx.x;
    const int jt = blockIdx.x, it = blockIdx.y, b = blockIdx.z;
    const int i0 = it * 4, j0 = jt * 16;

    for (int t = tid; t < 6 * 18 * 16; t += 256) {
        int r = t / 288, rem = t % 288, p = rem >> 4, q = rem & 15;
        int gi = i0 - 1 + r, gj = j0 - 1 + p;
        f16x8 v = {0, 0, 0, 0, 0, 0, 0, 0};
        if (((unsigned)gi < 256u) && ((unsigned)gj < 256u))
            v = *(const f16x8*)&in[(((size_t)b * 256 + gi) * 256 + gj) * 128 + q * 8];
        *(f16x8*)&Al[(r * 18 + p) * 136 + q * 8] = v;
    }
    __syncthreads();

    const int lane = tid & 63, wid = tid >> 6;
    const int l16 = lane & 15, quad = lane >> 4;
    f32x4 acc = {};
    const int DR[5] = {1, 0, 2, 1, 1}, DP[5] = {1, 1, 1, 0, 2};

#pragma unroll
    for (int ks = 0; ks < 20; ++ks) {
        const int tap = ks >> 2, kc = ks & 3;
        const int koff = kc * 32 + quad * 8;
        f16x8 bf = *(const f16x8*)&W4g[(size_t)(tap * 16 + l16) * 128 + koff];
        f16x8 af = *(const f16x8*)&Al[((DR[tap] + wid) * 18 + DP[tap] + l16) * 136 + koff];
        acc = __builtin_amdgcn_mfma_f32_16x16x32_f16(af, bf, acc, 0, 0, 0);
    }

    if (l16 < 6) {
        const float bb = bias[l16];
        const int i = i0 + wid;
#pragma unroll
        for (int vi = 0; vi < 4; ++vi) {
            int jj = j0 + quad * 4 + vi;
            outp[(((size_t)b * 6 + l16) << 16) + i * 256 + jj] = acc[vi] + bb;
        }
    }
}

extern "C" void kernel_launch(void* const* d_in, const int* in_sizes, int n_in,
                              void* d_out, int out_size, void* d_ws, size_t ws_size,
                              hipStream_t stream) {
    const float* x  = (const float*)d_in[0];
    const float* w1 = (const float*)d_in[1];
    const float* b1 = (const float*)d_in[2];
    const float* w2 = (const float*)d_in[3];
    const float* b2 = (const float*)d_in[4];
    const float* w3 = (const float*)d_in[5];
    const float* b3 = (const float*)d_in[6];
    const float* w4 = (const float*)d_in[7];
    const float* b4 = (const float*)d_in[8];
    float* out = (float*)d_out;

    const size_t act = (size_t)BB * HH * WW * 128;
    _Float16* A1 = (_Float16*)d_ws;
    _Float16* A2 = A1 + act;                    // exactly 268435456 B total

    prep<<<696, 256, 0, stream>>>(w1, w2, w3, w4);
    dim3 blk(256, 1, 1);
    dim3 gm(16, 32, 8);                         // 16-px x 8-row tiles
    g1<<<gm, blk, 0, stream>>>(x, b1, A1);
    gmid<2><<<gm, blk, 0, stream>>>(A1, b2, A2);
    gmid<3><<<gm, blk, 0, stream>>>(A2, b3, A1);
    g4<<<dim3(16, 64, 8), blk, 0, stream>>>(A1, b4, out);
}